// Round 3
// baseline (2299.963 us; speedup 1.0000x reference)
//
#include <hip/hip_runtime.h>
#include <cstddef>

#define NN 1024
#define DD 6
#define TT 60
#define HH 64
#define NEGV  (-10000.0f)
#define SLOPEV (0.01f)
#define SS 2            // GRU samples per block
#define NTHR 576        // 9 waves

__device__ __forceinline__ float sig_(float x)  { return 1.0f / (1.0f + __expf(-x)); }
__device__ __forceinline__ float tanh_(float x) { return 1.0f - 2.0f / (__expf(2.0f * x) + 1.0f); }

// ---------------------------------------------------------------------------
// k_main: even blocks = GRU (pipelined 2-layer recurrence, SS samples);
//         odd  blocks = relation-tensor streaming (1 thread per (i,j) pair,
//         16 float4 loads in flight -> latency covered).
// ---------------------------------------------------------------------------
__global__ __launch_bounds__(NTHR, 4)
void k_main(const float* __restrict__ x, const float* __restrict__ rel,
            const float* __restrict__ W, const float* __restrict__ fc_w,
            const float* __restrict__ Wih0, const float* __restrict__ Whh0,
            const float* __restrict__ bih0, const float* __restrict__ bhh0,
            const float* __restrict__ Wih1, const float* __restrict__ Whh1,
            const float* __restrict__ bih1, const float* __restrict__ bhh1,
            float* __restrict__ sa, float* __restrict__ sb,
            float* __restrict__ hdot, float* __restrict__ hb,
            float* __restrict__ sr, float* __restrict__ ssum)
{
    const int tid = threadIdx.x;

    if (blockIdx.x & 1) {
        // ---------------- relation streaming ----------------
        const int rb = blockIdx.x >> 1;                  // 0..511
        const size_t g = (size_t)rb * NTHR + tid;        // 0..294911
        for (size_t p = g; p < (size_t)NN * NN; p += (size_t)512 * NTHR) {
            const float4* base = (const float4*)(rel + p * 64);
            float4 v[16];
            #pragma unroll
            for (int k = 0; k < 16; ++k) v[k] = base[k];   // 16 loads batched
            float dt0 = 0.f, dt1 = 0.f, dt2 = 0.f, dt3 = 0.f;
            float sm0 = 0.f, sm1 = 0.f, sm2 = 0.f, sm3 = 0.f;
            #pragma unroll
            for (int k = 0; k < 16; k += 4) {
                const float4 w0 = ((const float4*)(W + 2 * HH))[k];
                const float4 w1 = ((const float4*)(W + 2 * HH))[k + 1];
                const float4 w2 = ((const float4*)(W + 2 * HH))[k + 2];
                const float4 w3 = ((const float4*)(W + 2 * HH))[k + 3];
                dt0 += v[k].x*w0.x + v[k].y*w0.y + v[k].z*w0.z + v[k].w*w0.w;
                dt1 += v[k+1].x*w1.x + v[k+1].y*w1.y + v[k+1].z*w1.z + v[k+1].w*w1.w;
                dt2 += v[k+2].x*w2.x + v[k+2].y*w2.y + v[k+2].z*w2.z + v[k+2].w*w2.w;
                dt3 += v[k+3].x*w3.x + v[k+3].y*w3.y + v[k+3].z*w3.z + v[k+3].w*w3.w;
                sm0 += v[k].x + v[k].y + v[k].z + v[k].w;
                sm1 += v[k+1].x + v[k+1].y + v[k+1].z + v[k+1].w;
                sm2 += v[k+2].x + v[k+2].y + v[k+2].z + v[k+2].w;
                sm3 += v[k+3].x + v[k+3].y + v[k+3].z + v[k+3].w;
            }
            sr[p]   = (dt0 + dt1) + (dt2 + dt3);
            ssum[p] = (sm0 + sm1) + (sm2 + sm3);
        }
        return;
    }

    // ---------------- GRU: SS samples, layer-1 pipelined 1 step behind ----------------
    const int gb = blockIdx.x >> 1;          // 0..511
    const int nb = gb * SS;

    __shared__ __align__(16) float xls[SS * DD * TT];      // 720
    __shared__ __align__(16) float h0buf[2][SS * HH];      // 256 (dbuf)
    __shared__ __align__(16) float h1buf[SS * HH];         // 128
    __shared__ __align__(16) float A0[SS][3 * HH];         // 384
    __shared__ __align__(16) float B0[SS][HH];             // 128
    __shared__ __align__(16) float G1[2][SS][3 * HH];      // 768
    __shared__ __align__(16) float H1n[2][SS][HH];         // 256

    for (int idx = tid; idx < SS * DD * TT; idx += NTHR)
        xls[idx] = x[(size_t)nb * DD * TT + idx];
    if (tid < 2 * SS * HH)            ((float*)h0buf)[tid] = 0.0f;
    else if (tid < 3 * SS * HH)       h1buf[tid - 2 * SS * HH] = 0.0f;

    // --- per-thread weights ---
    float wr0[HH], wi0[DD];  float bi0 = 0.f, bh0 = 0.f;        // group0
    float wih1r[32], whh1r[32]; float bi1j = 0.f, bh1j = 0.f;   // group1
    int half = 0, j1 = 0;

    if (tid < 192) {
        const int j = tid;
        #pragma unroll
        for (int kk = 0; kk < HH / 4; ++kk) {
            const float4 v = *(const float4*)(Whh0 + (size_t)j * HH + kk * 4);
            wr0[4*kk] = v.x; wr0[4*kk+1] = v.y; wr0[4*kk+2] = v.z; wr0[4*kk+3] = v.w;
        }
        #pragma unroll
        for (int d = 0; d < DD; ++d) wi0[d] = Wih0[j * DD + d];
        bi0 = bih0[j]; bh0 = bhh0[j];
    } else {
        const int u = tid - 192;
        half = (u >= 192) ? 1 : 0;
        j1   = u - half * 192;
        #pragma unroll
        for (int q = 0; q < 8; ++q) {
            const float4 a = *(const float4*)(Wih1 + (size_t)j1 * HH + half * 32 + q * 4);
            wih1r[4*q] = a.x; wih1r[4*q+1] = a.y; wih1r[4*q+2] = a.z; wih1r[4*q+3] = a.w;
            const float4 c = *(const float4*)(Whh1 + (size_t)j1 * HH + half * 32 + q * 4);
            whh1r[4*q] = c.x; whh1r[4*q+1] = c.y; whh1r[4*q+2] = c.z; whh1r[4*q+3] = c.w;
        }
        if (half == 0) { bi1j = bih1[j1]; bh1j = bhh1[j1]; }
    }
    __syncthreads();

    for (int i = 0; i <= TT; ++i) {
        const int pb = (i + 1) & 1;          // previous h0 buffer == (i-1)&1
        // ---------- phase A: gate partials ----------
        if (tid < 192) {
            if (i < TT) {
                const int j = tid;
                float hg[SS], xg[SS];
                #pragma unroll
                for (int s = 0; s < SS; ++s) { hg[s] = bh0; xg[s] = bi0; }
                const float4* hp = (const float4*)h0buf[pb];
                #pragma unroll
                for (int kk = 0; kk < HH / 4; ++kk) {
                    #pragma unroll
                    for (int s = 0; s < SS; ++s) {
                        const float4 v = hp[s * 16 + kk];
                        hg[s] += wr0[4*kk]*v.x + wr0[4*kk+1]*v.y + wr0[4*kk+2]*v.z + wr0[4*kk+3]*v.w;
                    }
                }
                #pragma unroll
                for (int s = 0; s < SS; ++s) {
                    #pragma unroll
                    for (int d = 0; d < DD; ++d) xg[s] += wi0[d] * xls[s * DD * TT + d * TT + i];
                    A0[s][j] = xg[s] + hg[s];
                    if (j >= 2 * HH) B0[s][j - 2 * HH] = hg[s];
                }
            }
        } else if (i >= 1) {
            float xp[SS], hq[SS];
            #pragma unroll
            for (int s = 0; s < SS; ++s) { xp[s] = bi1j; hq[s] = bh1j; }
            const float4* h0p = (const float4*)h0buf[pb];
            const float4* h1p = (const float4*)h1buf;
            #pragma unroll
            for (int q = 0; q < 8; ++q) {
                #pragma unroll
                for (int s = 0; s < SS; ++s) {
                    const float4 a = h0p[s * 16 + half * 8 + q];
                    const float4 c = h1p[s * 16 + half * 8 + q];
                    xp[s] += wih1r[4*q]*a.x + wih1r[4*q+1]*a.y + wih1r[4*q+2]*a.z + wih1r[4*q+3]*a.w;
                    hq[s] += whh1r[4*q]*c.x + whh1r[4*q+1]*c.y + whh1r[4*q+2]*c.z + whh1r[4*q+3]*c.w;
                }
            }
            #pragma unroll
            for (int s = 0; s < SS; ++s) {
                G1[half][s][j1] = xp[s] + hq[s];
                if (j1 >= 2 * HH) H1n[half][s][j1 - 2 * HH] = hq[s];
            }
        }
        __syncthreads();
        // ---------- phase B: activations / state update ----------
        if (i < TT && tid < SS * HH) {
            const int s = tid >> 6, jj = tid & 63;
            const float r  = sig_(A0[s][jj]);
            const float z  = sig_(A0[s][HH + jj]);
            const float hn = B0[s][jj];
            const float nv = tanh_(A0[s][2 * HH + jj] - hn + r * hn);
            h0buf[i & 1][s * HH + jj] = (1.0f - z) * nv + z * h0buf[pb][s * HH + jj];
        }
        if (i >= 1 && tid >= 192 && tid < 192 + SS * HH) {
            const int v = tid - 192;
            const int s = v >> 6, jj = v & 63;
            const float gr = G1[0][s][jj]          + G1[1][s][jj];
            const float gz = G1[0][s][HH + jj]     + G1[1][s][HH + jj];
            const float gn = G1[0][s][2 * HH + jj] + G1[1][s][2 * HH + jj];
            const float hn = H1n[0][s][jj]         + H1n[1][s][jj];
            const float r  = sig_(gr);
            const float z  = sig_(gz);
            const float nv = tanh_(gn - hn + r * hn);
            h1buf[s * HH + jj] = (1.0f - z) * nv + z * h1buf[s * HH + jj];
        }
        __syncthreads();
    }

    // ---------- epilogue: per-sample scalars ----------
    if (tid < SS * HH) {
        const int s = tid >> 6, jj = tid & 63;     // wave s, lane jj
        const float hv = h1buf[s * HH + jj];
        float pa = hv * W[jj];
        float pb2 = hv * W[HH + jj];
        float pc = hv * fc_w[jj];
        float pd = hv * fc_w[HH + jj];
        #pragma unroll
        for (int off = 32; off >= 1; off >>= 1) {
            pa  += __shfl_down(pa, off);
            pb2 += __shfl_down(pb2, off);
            pc  += __shfl_down(pc, off);
            pd  += __shfl_down(pd, off);
        }
        if (jj == 0) {
            sa[nb + s] = pa; sb[nb + s] = pb2;
            hdot[nb + s] = pc; hb[nb + s] = pd;
        }
    }
}

// ---------------------------------------------------------------------------
// k2: per row i — masked leaky scores, exact masked-softmax semantics,
// out_i = hdot_i + (sum_j e_j*m_j*hb_j)/denom + fc_b.
// ---------------------------------------------------------------------------
__global__ __launch_bounds__(256)
void k2(const float* __restrict__ sa, const float* __restrict__ sb,
        const float* __restrict__ hdot, const float* __restrict__ hb,
        const float* __restrict__ sr, const float* __restrict__ ssum,
        const float* __restrict__ bscal, const float* __restrict__ fc_b,
        float* __restrict__ out)
{
    __shared__ float red[12];
    const int i   = blockIdx.x;
    const int tid = threadIdx.x;
    const int j4  = tid * 4;
    const float sai = sa[i] + bscal[0];

    const float4 srv = *(const float4*)(sr   + (size_t)i * NN + j4);
    const float4 ssv = *(const float4*)(ssum + (size_t)i * NN + j4);
    const float4 sbv = *(const float4*)(sb + j4);

    float tv[4], mk[4];
    float mloc = -3.4e38f;
    {
        const float srq[4] = {srv.x, srv.y, srv.z, srv.w};
        const float ssq[4] = {ssv.x, ssv.y, ssv.z, ssv.w};
        const float sbq[4] = {sbv.x, sbv.y, sbv.z, sbv.w};
        #pragma unroll
        for (int q = 0; q < 4; ++q) {
            float w = sai + sbq[q] + srq[q];
            w = (w >= 0.0f) ? w : SLOPEV * w;
            const float m = (ssq[q] != 0.0f) ? 1.0f : 0.0f;
            float t = m * w;
            t = (t == 0.0f) ? NEGV : t;
            tv[q] = t; mk[q] = m;
            mloc = fmaxf(mloc, t);
        }
    }
    #pragma unroll
    for (int off = 32; off >= 1; off >>= 1) mloc = fmaxf(mloc, __shfl_xor(mloc, off));
    if ((tid & 63) == 0) red[tid >> 6] = mloc;
    __syncthreads();
    const float mx = fmaxf(fmaxf(red[0], red[1]), fmaxf(red[2], red[3]));

    const float4 hbv = *(const float4*)(hb + j4);
    const float hbq[4] = {hbv.x, hbv.y, hbv.z, hbv.w};
    float sloc = 0.0f, vloc = 0.0f;
    #pragma unroll
    for (int q = 0; q < 4; ++q) {
        const float e = __expf(tv[q] - mx);   // masked -> exp(-1e4 - mx) == 0
        sloc += e;
        vloc += e * mk[q] * hbq[q];
    }
    #pragma unroll
    for (int off = 32; off >= 1; off >>= 1) {
        sloc += __shfl_xor(sloc, off);
        vloc += __shfl_xor(vloc, off);
    }
    if ((tid & 63) == 0) { red[4 + (tid >> 6)] = sloc; red[8 + (tid >> 6)] = vloc; }
    __syncthreads();
    if (tid == 0) {
        const float denom = red[4] + red[5] + red[6] + red[7];
        const float vsum  = red[8] + red[9] + red[10] + red[11];
        out[i] = hdot[i] + vsum / denom + fc_b[0];
    }
}

// ---------------------------------------------------------------------------
extern "C" void kernel_launch(void* const* d_in, const int* in_sizes, int n_in,
                              void* d_out, int out_size, void* d_ws, size_t ws_size,
                              hipStream_t stream)
{
    const float* x     = (const float*)d_in[0];
    const float* rel   = (const float*)d_in[1];
    const float* W     = (const float*)d_in[2];
    const float* b     = (const float*)d_in[3];
    const float* fc_w  = (const float*)d_in[4];
    const float* fc_b  = (const float*)d_in[5];
    const float* Wih0  = (const float*)d_in[6];
    const float* Whh0  = (const float*)d_in[7];
    const float* bih0  = (const float*)d_in[8];
    const float* bhh0  = (const float*)d_in[9];
    const float* Wih1  = (const float*)d_in[10];
    const float* Whh1  = (const float*)d_in[11];
    const float* bih1  = (const float*)d_in[12];
    const float* bhh1  = (const float*)d_in[13];

    float* ws   = (float*)d_ws;
    float* sa   = ws;                         // 1024
    float* sb   = sa   + NN;                  // 1024
    float* hdot = sb   + NN;                  // 1024
    float* hb   = hdot + NN;                  // 1024
    float* sr   = hb   + NN;                  // 1024*1024
    float* ssum = sr   + (size_t)NN * NN;     // 1024*1024

    k_main<<<1024, NTHR, 0, stream>>>(x, rel, W, fc_w,
                                      Wih0, Whh0, bih0, bhh0,
                                      Wih1, Whh1, bih1, bhh1,
                                      sa, sb, hdot, hb, sr, ssum);
    k2<<<NN, 256, 0, stream>>>(sa, sb, hdot, hb, sr, ssum,
                               b, fc_b, (float*)d_out);
}

// Round 4
// 649.683 us; speedup vs baseline: 3.5401x; 3.5401x over previous
//
#include <hip/hip_runtime.h>
#include <cstddef>

#define NN 1024
#define DD 6
#define TT 60
#define HH 64
#define NEGV  (-10000.0f)
#define SLOPEV (0.01f)
#define NTH 384

__device__ __forceinline__ float sig_(float x)  { return 1.0f / (1.0f + __expf(-x)); }
__device__ __forceinline__ float tanh_(float x) { return 1.0f - 2.0f / (__expf(2.0f * x) + 1.0f); }

// ---------------------------------------------------------------------------
// k_main: odd blocks stream the 268 MB relation tensor (1 thread/pair,
// 16 float4 in registers -> 16KB/wave in flight); even blocks run the 2-layer
// GRU for 2 samples with half-row-split weights (<=64 wt floats/thread).
// ---------------------------------------------------------------------------
__global__ __launch_bounds__(NTH)
void k_main(const float* __restrict__ x, const float* __restrict__ rel,
            const float* __restrict__ W, const float* __restrict__ fc_w,
            const float* __restrict__ Wih0, const float* __restrict__ Whh0,
            const float* __restrict__ bih0, const float* __restrict__ bhh0,
            const float* __restrict__ Wih1, const float* __restrict__ Whh1,
            const float* __restrict__ bih1, const float* __restrict__ bhh1,
            float* __restrict__ sa, float* __restrict__ sb,
            float* __restrict__ hdot, float* __restrict__ hb,
            float* __restrict__ sr, float* __restrict__ ssum)
{
    __shared__ __align__(16) float smem[9680];
    const int tid = threadIdx.x;

    if (blockIdx.x & 1) {
        // ---------------- relation streaming ----------------
        float* Wv = smem;                       // 64 floats of W[128:192]
        if (tid < 64) Wv[tid] = W[2 * HH + tid];
        __syncthreads();
        const size_t g = (size_t)(blockIdx.x >> 1) * NTH + tid;
        for (size_t p = g; p < (size_t)NN * NN; p += (size_t)512 * NTH) {
            const float4* base = (const float4*)(rel + p * 64);
            float4 v[16];
            #pragma unroll
            for (int k = 0; k < 16; ++k) v[k] = base[k];
            float4 dt = {0.f, 0.f, 0.f, 0.f};
            float4 sm = {0.f, 0.f, 0.f, 0.f};
            #pragma unroll
            for (int k = 0; k < 16; ++k) {
                const float4 w4 = ((const float4*)Wv)[k];
                dt.x += v[k].x * w4.x; dt.y += v[k].y * w4.y;
                dt.z += v[k].z * w4.z; dt.w += v[k].w * w4.w;
                sm.x += v[k].x; sm.y += v[k].y; sm.z += v[k].z; sm.w += v[k].w;
            }
            sr[p]   = (dt.x + dt.y) + (dt.z + dt.w);
            ssum[p] = (sm.x + sm.y) + (sm.z + sm.w);
        }
        return;
    }

    // ---------------- GRU: 2 samples, half-row split ----------------
    float* xls   = smem;            // 720  [s][d][t]
    float* h0seq = smem + 720;      // 7680 [s][t][jj]
    float* h0c   = smem + 8400;     // 128  [s][jj]
    float* h1c   = smem + 8528;     // 128
    float* Gp    = smem + 8656;     // 512  [half][s][j<128]
    float* Xp    = smem + 9168;     // 256  [half][s][jj]
    float* Hp    = smem + 9424;     // 256  [half][s][jj]

    const int nb   = (blockIdx.x >> 1) * 2;
    const int half = tid >= 192;          // wave-uniform (waves 0-2 vs 3-5)
    const int j    = tid - half * 192;    // gate row 0..191

    for (int idx = tid; idx < 2 * DD * TT; idx += NTH)
        xls[idx] = x[(size_t)nb * DD * TT + idx];
    if (tid < 128) { h0c[tid] = 0.f; h1c[tid] = 0.f; }

    // ---- phase-0 weights: half of Whh0 row j (32 floats) + Wih0 row ----
    float2 w0h[16]; float wi0[DD];
    float bsum0 = 0.f, bi0n = 0.f, bh0n = 0.f;
    {
        const float2* row = (const float2*)(Whh0 + (size_t)j * HH) + half * 16;
        #pragma unroll
        for (int q = 0; q < 16; ++q) w0h[q] = row[q];
        if (!half) {
            #pragma unroll
            for (int d = 0; d < DD; ++d) wi0[d] = Wih0[j * DD + d];
            bsum0 = bih0[j] + bhh0[j]; bi0n = bih0[j]; bh0n = bhh0[j];
        }
    }
    __syncthreads();

    for (int t = 0; t < TT; ++t) {
        float2 a0 = {0.f, 0.f}, a1 = {0.f, 0.f};
        const float2* hv0 = (const float2*)h0c + half * 16;
        const float2* hv1 = (const float2*)(h0c + 64) + half * 16;
        #pragma unroll
        for (int q = 0; q < 16; ++q) {
            const float2 w = w0h[q];
            const float2 p0 = hv0[q], p1 = hv1[q];
            a0.x += w.x * p0.x; a0.y += w.y * p0.y;
            a1.x += w.x * p1.x; a1.y += w.y * p1.y;
        }
        const float hg0 = a0.x + a0.y, hg1 = a1.x + a1.y;
        if (!half) {
            float xg0 = 0.f, xg1 = 0.f;
            #pragma unroll
            for (int d = 0; d < DD; ++d) {
                xg0 += wi0[d] * xls[d * TT + t];
                xg1 += wi0[d] * xls[DD * TT + d * TT + t];
            }
            if (j < 128) { Gp[j] = xg0 + hg0 + bsum0; Gp[128 + j] = xg1 + hg1 + bsum0; }
            else {
                const int jj = j - 128;
                Xp[jj] = xg0 + bi0n;      Xp[64 + jj] = xg1 + bi0n;
                Hp[jj] = hg0 + bh0n;      Hp[64 + jj] = hg1 + bh0n;
            }
        } else {
            if (j < 128) { Gp[256 + j] = hg0; Gp[384 + j] = hg1; }
            else { const int jj = j - 128; Hp[128 + jj] = hg0; Hp[192 + jj] = hg1; }
        }
        __syncthreads();
        if (tid < 128) {
            const int s = tid >> 6, jj = tid & 63;
            const float r  = sig_(Gp[s * 128 + jj] + Gp[256 + s * 128 + jj]);
            const float z  = sig_(Gp[s * 128 + 64 + jj] + Gp[256 + s * 128 + 64 + jj]);
            const float hn = Hp[s * 64 + jj] + Hp[128 + s * 64 + jj];
            const float nv = tanh_(Xp[s * 64 + jj] + r * hn);
            const float hnew = (1.f - z) * nv + z * h0c[s * 64 + jj];
            h0c[s * 64 + jj] = hnew;
            h0seq[(s * TT + t) * 64 + jj] = hnew;
        }
        __syncthreads();
    }

    // ---- phase-1 weights: halves of Wih1 & Whh1 rows (64 floats) ----
    float2 wi1h[16], w1h[16];
    float bs1 = 0.f, bi1n = 0.f, bh1n = 0.f;
    {
        const float2* ra = (const float2*)(Wih1 + (size_t)j * HH) + half * 16;
        const float2* rc = (const float2*)(Whh1 + (size_t)j * HH) + half * 16;
        #pragma unroll
        for (int q = 0; q < 16; ++q) { wi1h[q] = ra[q]; w1h[q] = rc[q]; }
        if (!half) { bs1 = bih1[j] + bhh1[j]; bi1n = bih1[j]; bh1n = bhh1[j]; }
    }

    for (int t = 0; t < TT; ++t) {
        float2 xa0 = {0.f,0.f}, xa1 = {0.f,0.f}, ha0 = {0.f,0.f}, ha1 = {0.f,0.f};
        const float2* q0 = (const float2*)(h0seq + t * 64) + half * 16;
        const float2* q1 = (const float2*)(h0seq + (TT + t) * 64) + half * 16;
        const float2* r0 = (const float2*)h1c + half * 16;
        const float2* r1 = (const float2*)(h1c + 64) + half * 16;
        #pragma unroll
        for (int q = 0; q < 16; ++q) {
            const float2 wa = wi1h[q], wc = w1h[q];
            const float2 u0 = q0[q], u1 = q1[q], v0 = r0[q], v1 = r1[q];
            xa0.x += wa.x * u0.x; xa0.y += wa.y * u0.y;
            xa1.x += wa.x * u1.x; xa1.y += wa.y * u1.y;
            ha0.x += wc.x * v0.x; ha0.y += wc.y * v0.y;
            ha1.x += wc.x * v1.x; ha1.y += wc.y * v1.y;
        }
        const float xg0 = xa0.x + xa0.y, xg1v = xa1.x + xa1.y;
        const float hg0 = ha0.x + ha0.y, hg1v = ha1.x + ha1.y;
        if (j < 128) {
            const float bb = half ? 0.f : bs1;
            Gp[half * 256 + j]       = xg0 + hg0 + bb;
            Gp[half * 256 + 128 + j] = xg1v + hg1v + bb;
        } else {
            const int jj = j - 128;
            const float bx = half ? 0.f : bi1n;
            const float bh = half ? 0.f : bh1n;
            Xp[half * 128 + jj]      = xg0 + bx;
            Xp[half * 128 + 64 + jj] = xg1v + bx;
            Hp[half * 128 + jj]      = hg0 + bh;
            Hp[half * 128 + 64 + jj] = hg1v + bh;
        }
        __syncthreads();
        if (tid < 128) {
            const int s = tid >> 6, jj = tid & 63;
            const float r  = sig_(Gp[s * 128 + jj] + Gp[256 + s * 128 + jj]);
            const float z  = sig_(Gp[s * 128 + 64 + jj] + Gp[256 + s * 128 + 64 + jj]);
            const float hn = Hp[s * 64 + jj] + Hp[128 + s * 64 + jj];
            const float xn = Xp[s * 64 + jj] + Xp[128 + s * 64 + jj];
            const float nv = tanh_(xn + r * hn);
            h1c[s * 64 + jj] = (1.f - z) * nv + z * h1c[s * 64 + jj];
        }
        __syncthreads();
    }

    // ---- epilogue: per-sample scalars ----
    if (tid < 128) {
        const int s = tid >> 6, jj = tid & 63;
        const float hv = h1c[s * 64 + jj];
        float pa = hv * W[jj];
        float pb = hv * W[HH + jj];
        float pc = hv * fc_w[jj];
        float pd = hv * fc_w[HH + jj];
        #pragma unroll
        for (int off = 32; off >= 1; off >>= 1) {
            pa += __shfl_down(pa, off);
            pb += __shfl_down(pb, off);
            pc += __shfl_down(pc, off);
            pd += __shfl_down(pd, off);
        }
        if (jj == 0) {
            sa[nb + s] = pa; sb[nb + s] = pb;
            hdot[nb + s] = pc; hb[nb + s] = pd;
        }
    }
}

// ---------------------------------------------------------------------------
// k2: per row i — masked leaky scores, exact masked-softmax semantics,
// out_i = hdot_i + (sum_j e_j*m_j*hb_j)/denom + fc_b.
// ---------------------------------------------------------------------------
__global__ __launch_bounds__(256)
void k2(const float* __restrict__ sa, const float* __restrict__ sb,
        const float* __restrict__ hdot, const float* __restrict__ hb,
        const float* __restrict__ sr, const float* __restrict__ ssum,
        const float* __restrict__ bscal, const float* __restrict__ fc_b,
        float* __restrict__ out)
{
    __shared__ float red[12];
    const int i   = blockIdx.x;
    const int tid = threadIdx.x;
    const int j4  = tid * 4;
    const float sai = sa[i] + bscal[0];

    const float4 srv = *(const float4*)(sr   + (size_t)i * NN + j4);
    const float4 ssv = *(const float4*)(ssum + (size_t)i * NN + j4);
    const float4 sbv = *(const float4*)(sb + j4);

    float tv[4], mk[4];
    float mloc = -3.4e38f;
    {
        const float srq[4] = {srv.x, srv.y, srv.z, srv.w};
        const float ssq[4] = {ssv.x, ssv.y, ssv.z, ssv.w};
        const float sbq[4] = {sbv.x, sbv.y, sbv.z, sbv.w};
        #pragma unroll
        for (int q = 0; q < 4; ++q) {
            float w = sai + sbq[q] + srq[q];
            w = (w >= 0.0f) ? w : SLOPEV * w;
            const float m = (ssq[q] != 0.0f) ? 1.0f : 0.0f;
            float t = m * w;
            t = (t == 0.0f) ? NEGV : t;
            tv[q] = t; mk[q] = m;
            mloc = fmaxf(mloc, t);
        }
    }
    #pragma unroll
    for (int off = 32; off >= 1; off >>= 1) mloc = fmaxf(mloc, __shfl_xor(mloc, off));
    if ((tid & 63) == 0) red[tid >> 6] = mloc;
    __syncthreads();
    const float mx = fmaxf(fmaxf(red[0], red[1]), fmaxf(red[2], red[3]));

    const float4 hbv = *(const float4*)(hb + j4);
    const float hbq[4] = {hbv.x, hbv.y, hbv.z, hbv.w};
    float sloc = 0.0f, vloc = 0.0f;
    #pragma unroll
    for (int q = 0; q < 4; ++q) {
        const float e = __expf(tv[q] - mx);   // masked -> exp(-1e4 - mx) == 0
        sloc += e;
        vloc += e * mk[q] * hbq[q];
    }
    #pragma unroll
    for (int off = 32; off >= 1; off >>= 1) {
        sloc += __shfl_xor(sloc, off);
        vloc += __shfl_xor(vloc, off);
    }
    if ((tid & 63) == 0) { red[4 + (tid >> 6)] = sloc; red[8 + (tid >> 6)] = vloc; }
    __syncthreads();
    if (tid == 0) {
        const float denom = red[4] + red[5] + red[6] + red[7];
        const float vsum  = red[8] + red[9] + red[10] + red[11];
        out[i] = hdot[i] + vsum / denom + fc_b[0];
    }
}

// ---------------------------------------------------------------------------
extern "C" void kernel_launch(void* const* d_in, const int* in_sizes, int n_in,
                              void* d_out, int out_size, void* d_ws, size_t ws_size,
                              hipStream_t stream)
{
    const float* x     = (const float*)d_in[0];
    const float* rel   = (const float*)d_in[1];
    const float* W     = (const float*)d_in[2];
    const float* b     = (const float*)d_in[3];
    const float* fc_w  = (const float*)d_in[4];
    const float* fc_b  = (const float*)d_in[5];
    const float* Wih0  = (const float*)d_in[6];
    const float* Whh0  = (const float*)d_in[7];
    const float* bih0  = (const float*)d_in[8];
    const float* bhh0  = (const float*)d_in[9];
    const float* Wih1  = (const float*)d_in[10];
    const float* Whh1  = (const float*)d_in[11];
    const float* bih1  = (const float*)d_in[12];
    const float* bhh1  = (const float*)d_in[13];

    float* ws   = (float*)d_ws;
    float* sa   = ws;                         // 1024
    float* sb   = sa   + NN;                  // 1024
    float* hdot = sb   + NN;                  // 1024
    float* hb   = hdot + NN;                  // 1024
    float* sr   = hb   + NN;                  // 1024*1024
    float* ssum = sr   + (size_t)NN * NN;     // 1024*1024

    k_main<<<1024, NTH, 0, stream>>>(x, rel, W, fc_w,
                                     Wih0, Whh0, bih0, bhh0,
                                     Wih1, Whh1, bih1, bhh1,
                                     sa, sb, hdot, hb, sr, ssum);
    k2<<<NN, 256, 0, stream>>>(sa, sb, hdot, hb, sr, ssum,
                               b, fc_b, (float*)d_out);
}